// Round 1
// baseline (4213.220 us; speedup 1.0000x reference)
//
#include <hip/hip_runtime.h>
#include <math.h>

#define TLEN 160000
#define NA 625      // n1 (time rows) / ka (freq elements)
#define NB 256      // n2 (time elements) / kb (freq rows)
#define TD 2500
#define KC 128      // conv half width (~5 sigma_t, sigma_t = 25.46)
#define NTAP 257
#define SROWS 337
#define TWO_PI 6.283185307179586f

struct c2 { float x, y; };

__device__ __forceinline__ c2 cmul(c2 a, c2 b){ return c2{a.x*b.x - a.y*b.y, a.x*b.y + a.y*b.x}; }
__device__ __forceinline__ c2 cadd(c2 a, c2 b){ return c2{a.x+b.x, a.y+b.y}; }
__device__ __forceinline__ c2 csub(c2 a, c2 b){ return c2{a.x-b.x, a.y-b.y}; }
__device__ __forceinline__ c2 cmac(c2 acc, c2 v, float wr, float wi){
  acc.x += v.x*wr - v.y*wi; acc.y += v.x*wi + v.y*wr; return acc;
}
__device__ __forceinline__ c2 cis(float ang){ c2 r; __sincosf(ang, &r.y, &r.x); return r; }
// LDS index swizzle to break power-of-2 bank strides
__device__ __forceinline__ int SW(int i){ return i + (i >> 4); }

__device__ __forceinline__ float omega_of(int k){
  return (k >= TLEN/2 ? (float)(k - TLEN) : (float)k) * (1.0f/(float)TLEN);
}
__device__ __forceinline__ float psi1_val(int j1, int k){
  float xi = 0.4f * exp2f(-(float)j1 * 0.0625f);
  float sig = xi * 0.04427378243f;               // 2^(1/16)-1
  float d = omega_of(k) - xi;
  return __expf(-d*d / (2.0f*sig*sig));
}
__device__ __forceinline__ float psi2_val(int j2, int k){
  float xi = 0.4f * exp2f(-(float)j2);
  float sig = 0.35f * xi;
  float d = omega_of(k) - xi;
  return __expf(-d*d / (2.0f*sig*sig));
}

template<int S>
__device__ __forceinline__ void dft4(c2& a0, c2& a1, c2& a2, c2& a3){
  c2 t0 = cadd(a0,a2), t1 = csub(a0,a2), t2 = cadd(a1,a3), t3 = csub(a1,a3);
  float fs = (float)S;
  a0 = cadd(t0,t2); a2 = csub(t0,t2);
  a1 = c2{t1.x - fs*t3.y, t1.y + fs*t3.x};
  a3 = c2{t1.x + fs*t3.y, t1.y - fs*t3.x};
}

template<int S>
__device__ __forceinline__ void dft5(const c2 a[5], c2 b[5]){
  const float C1 = 0.30901699437494742f, C2 = -0.80901699437494745f;
  const float S1 = 0.95105651629515353f * (float)S, S2 = 0.58778525229247314f * (float)S;
  b[0] = cadd(cadd(a[0],a[1]), cadd(cadd(a[2],a[3]),a[4]));
  c2 r;
  r = a[0]; r = cmac(r,a[1],C1, S1); r = cmac(r,a[2],C2, S2); r = cmac(r,a[3],C2,-S2); r = cmac(r,a[4],C1,-S1); b[1]=r;
  r = a[0]; r = cmac(r,a[1],C2, S2); r = cmac(r,a[2],C1,-S1); r = cmac(r,a[3],C1, S1); r = cmac(r,a[4],C2,-S2); b[2]=r;
  r = a[0]; r = cmac(r,a[1],C2,-S2); r = cmac(r,a[2],C1, S1); r = cmac(r,a[3],C1,-S1); r = cmac(r,a[4],C2, S2); b[3]=r;
  r = a[0]; r = cmac(r,a[1],C1,-S1); r = cmac(r,a[2],C2,-S2); r = cmac(r,a[3],C2, S2); r = cmac(r,a[4],C1, S1); b[4]=r;
}

// ---------------- 256-point row FFT (radix-4 Stockham), one row per 64-thread block ----------------
// INMODE: 0 = complex rows, 1 = real rows (scrambled), 2 = natural-order real gather (x)
// OUTMODE: 0 = complex + row twiddle e^{S*2pi*i*n1*kb/T} (first forward stage)
//          1 = |.| * (1/T) -> float rows (last inverse stage)
template<int S, int INMODE, int OUTMODE>
__global__ __launch_bounds__(64) void k_fft256(const void* __restrict__ inp, void* __restrict__ outp){
  __shared__ c2 lds[2][272];
  int g = blockIdx.x;
  int arr = g / NA, n1 = g - arr*NA;
  int j = threadIdx.x;
  c2 v[4];
  if (INMODE == 0){
    const c2* ip = (const c2*)inp + (size_t)arr*TLEN + (size_t)n1*NB;
    #pragma unroll
    for (int q=0;q<4;q++) v[q] = ip[j + 64*q];
  } else if (INMODE == 1){
    const float* ip = (const float*)inp + (size_t)arr*TLEN + (size_t)n1*NB;
    #pragma unroll
    for (int q=0;q<4;q++) v[q] = c2{ip[j + 64*q], 0.0f};
  } else {
    const float* ip = (const float*)inp + (size_t)arr*TLEN;
    #pragma unroll
    for (int q=0;q<4;q++) v[q] = c2{ip[n1 + NA*(j + 64*q)], 0.0f};
  }
  dft4<S>(v[0],v[1],v[2],v[3]);
  #pragma unroll
  for (int r=0;r<4;r++) lds[0][SW(4*j + r)] = v[r];
  __syncthreads();
  { // L = 4
    int k = j & 3;
    c2 w = cis((float)S * TWO_PI * (float)k * (1.0f/16.0f));
    c2 w2 = cmul(w,w), w3 = cmul(w2,w);
    v[0] = lds[0][SW(j)];
    v[1] = cmul(lds[0][SW(j+64)], w);
    v[2] = cmul(lds[0][SW(j+128)], w2);
    v[3] = cmul(lds[0][SW(j+192)], w3);
    dft4<S>(v[0],v[1],v[2],v[3]);
    int base = 4*(j-k)+k;
    #pragma unroll
    for (int r=0;r<4;r++) lds[1][SW(base + 4*r)] = v[r];
  }
  __syncthreads();
  { // L = 16
    int k = j & 15;
    c2 w = cis((float)S * TWO_PI * (float)k * (1.0f/64.0f));
    c2 w2 = cmul(w,w), w3 = cmul(w2,w);
    v[0] = lds[1][SW(j)];
    v[1] = cmul(lds[1][SW(j+64)], w);
    v[2] = cmul(lds[1][SW(j+128)], w2);
    v[3] = cmul(lds[1][SW(j+192)], w3);
    dft4<S>(v[0],v[1],v[2],v[3]);
    int base = 4*(j-k)+k;
    #pragma unroll
    for (int r=0;r<4;r++) lds[0][SW(base + 16*r)] = v[r];
  }
  __syncthreads();
  { // L = 64 (k = j), outputs kb = j + 64r
    c2 w = cis((float)S * TWO_PI * (float)j * (1.0f/256.0f));
    c2 w2 = cmul(w,w), w3 = cmul(w2,w);
    v[0] = lds[0][SW(j)];
    v[1] = cmul(lds[0][SW(j+64)], w);
    v[2] = cmul(lds[0][SW(j+128)], w2);
    v[3] = cmul(lds[0][SW(j+192)], w3);
    dft4<S>(v[0],v[1],v[2],v[3]);
    if (OUTMODE == 0){
      c2* op = (c2*)outp + (size_t)arr*TLEN + (size_t)n1*NB;
      #pragma unroll
      for (int r=0;r<4;r++){
        int kb = j + 64*r;
        c2 tw = cis((float)S * TWO_PI * (float)(n1*kb) * (1.0f/160000.0f));
        op[kb] = cmul(v[r], tw);
      }
    } else {
      float* op = (float*)outp + (size_t)arr*TLEN + (size_t)n1*NB;
      #pragma unroll
      for (int r=0;r<4;r++){
        c2 z = v[r];
        op[j + 64*r] = sqrtf(z.x*z.x + z.y*z.y) * (1.0f/160000.0f);
      }
    }
  }
}

// ---------------- 625-point row FFT (radix-5 Stockham), one row per 128-thread block ----------------
// FILT: 0 none (input array = task i), 1 psi1 (input = Xf[b]), 2 psi2 (input = U1h[slot])
// TW: multiply output element n1 of row kb by e^{S*2pi*i*n1*kb/T}
template<int S, int FILT, int TW>
__global__ __launch_bounds__(128) void k_fft625(const c2* __restrict__ inp, c2* __restrict__ outp,
                                                int cblk, int BLK, int nj2, int j2base, int scBase){
  __shared__ c2 lds[2][672];
  int g = blockIdx.x;
  int i = g / NB, kb = g - i*NB;
  int j = threadIdx.x;
  c2 a[5], b[5];
  if (j < 125){
    const c2* ip;
    int j1 = 0, j2 = 0;
    if (FILT == 0){
      ip = inp + (size_t)i*TLEN;
    } else if (FILT == 1){
      int bt = i / BLK; j1 = cblk*BLK + (i - bt*BLK);
      ip = inp + (size_t)bt*TLEN;
    } else {
      int g2 = scBase + i;
      int npb = BLK*nj2;
      int bt = g2 / npb, rr = g2 - bt*npb;
      int jloc = rr / nj2; j2 = j2base + (rr - jloc*nj2);
      ip = inp + (size_t)(bt*BLK + jloc)*TLEN;
    }
    ip += (size_t)kb*NA;
    #pragma unroll
    for (int q=0;q<5;q++){
      int ka = j + 125*q;
      c2 val = ip[ka];
      if (FILT == 1){ float f = psi1_val(j1, kb + 256*ka); val.x *= f; val.y *= f; }
      if (FILT == 2){ float f = psi2_val(j2, kb + 256*ka); val.x *= f; val.y *= f; }
      a[q] = val;
    }
    dft5<S>(a, b);
    #pragma unroll
    for (int r=0;r<5;r++) lds[0][SW(5*j + r)] = b[r];
  }
  __syncthreads();
  if (j < 125){ // L = 5
    int k = j % 5;
    c2 w = cis((float)S * TWO_PI * (float)k * (1.0f/25.0f));
    c2 w2 = cmul(w,w), w3 = cmul(w2,w), w4 = cmul(w3,w);
    a[0] = lds[0][SW(j)];
    a[1] = cmul(lds[0][SW(j+125)], w);
    a[2] = cmul(lds[0][SW(j+250)], w2);
    a[3] = cmul(lds[0][SW(j+375)], w3);
    a[4] = cmul(lds[0][SW(j+500)], w4);
    dft5<S>(a, b);
    int base = 5*(j-k)+k;
    #pragma unroll
    for (int r=0;r<5;r++) lds[1][SW(base + 5*r)] = b[r];
  }
  __syncthreads();
  if (j < 125){ // L = 25
    int k = j % 25;
    c2 w = cis((float)S * TWO_PI * (float)k * (1.0f/125.0f));
    c2 w2 = cmul(w,w), w3 = cmul(w2,w), w4 = cmul(w3,w);
    a[0] = lds[1][SW(j)];
    a[1] = cmul(lds[1][SW(j+125)], w);
    a[2] = cmul(lds[1][SW(j+250)], w2);
    a[3] = cmul(lds[1][SW(j+375)], w3);
    a[4] = cmul(lds[1][SW(j+500)], w4);
    dft5<S>(a, b);
    int base = 5*(j-k)+k;
    #pragma unroll
    for (int r=0;r<5;r++) lds[0][SW(base + 25*r)] = b[r];
  }
  __syncthreads();
  if (j < 125){ // L = 125 (k = j), outputs n1 = j + 125r
    c2 w = cis((float)S * TWO_PI * (float)j * (1.0f/625.0f));
    c2 w2 = cmul(w,w), w3 = cmul(w2,w), w4 = cmul(w3,w);
    a[0] = lds[0][SW(j)];
    a[1] = cmul(lds[0][SW(j+125)], w);
    a[2] = cmul(lds[0][SW(j+250)], w2);
    a[3] = cmul(lds[0][SW(j+375)], w3);
    a[4] = cmul(lds[0][SW(j+500)], w4);
    dft5<S>(a, b);
    c2* op = outp + (size_t)i*TLEN + (size_t)kb*NA;
    #pragma unroll
    for (int r=0;r<5;r++){
      int n1 = j + 125*r;
      c2 z = b[r];
      if (TW){
        c2 tw = cis((float)S * TWO_PI * (float)(n1*kb) * (1.0f/160000.0f));
        z = cmul(z, tw);
      }
      op[n1] = z;
    }
  }
}

// ---------------- complex transpose [R][C] -> [C][R], per array ----------------
__global__ __launch_bounds__(256) void k_transpose(const c2* __restrict__ in, c2* __restrict__ out,
                                                   int R, int C, int tilesR, int tilesC){
  __shared__ c2 tile[32][33];
  int bi = blockIdx.x;
  int arr = bi / (tilesR*tilesC);
  int tt = bi - arr*(tilesR*tilesC);
  int tr = tt / tilesC, tc = tt - tr*tilesC;
  const c2* ip = in + (size_t)arr*TLEN;
  c2* op = out + (size_t)arr*TLEN;
  int tx = threadIdx.x & 31, ty = threadIdx.x >> 5;
  #pragma unroll
  for (int i=0;i<4;i++){
    int r = tr*32 + ty + i*8, cc = tc*32 + tx;
    if (r < R && cc < C) tile[ty+i*8][tx] = ip[(size_t)r*C + cc];
  }
  __syncthreads();
  #pragma unroll
  for (int i=0;i<4;i++){
    int r = tc*32 + ty + i*8, cc = tr*32 + tx;
    if (r < C && cc < R) op[(size_t)r*R + cc] = tile[tx][ty+i*8];
  }
}

// ---------------- Gaussian lowpass + decimate-by-64 (time domain) ----------------
// LAYOUT: 0 natural order, 1 scrambled ([n1][n2], n = n1 + 625*n2)
// MODE: 0 -> S0 row, 1 -> S1 rows, 2 -> S2 rows
template<int LAYOUT, int MODE>
__global__ __launch_bounds__(256) void k_conv(const float* __restrict__ inp, float* __restrict__ S,
                                              int cblk, int BLK, int nj2, int j2base, int scBase){
  __shared__ float w[NTAP];
  for (int i=threadIdx.x; i<NTAP; i+=256){
    float d = (float)(i - KC);
    w[i] = 0.015666427f * __expf(-7.7106284e-4f * d * d);  // sigma*sqrt(2pi)*exp(-2 pi^2 sigma^2 m^2)
  }
  __syncthreads();
  int g = blockIdx.x;
  int arr = g / 10;
  int t = (g - arr*10)*256 + threadIdx.x;
  if (t >= TD) return;
  int srow;
  if (MODE == 0){
    srow = arr * SROWS;
  } else if (MODE == 1){
    int b = arr / BLK; int j1 = cblk*BLK + (arr - b*BLK);
    srow = b*SROWS + 1 + j1;
  } else {
    int g2 = scBase + arr; int npb = BLK*nj2;
    int b = g2/npb, rr = g2 - b*npb;
    int jloc = rr/nj2; int j2 = j2base + (rr - jloc*nj2);
    int j1 = cblk*BLK + jloc;
    int full = j1 >> 4;
    int cum = 16*(5*full - (full*(full-1))/2) + (j1 & 15)*(5 - full);
    int P = cum + j2 - full - 1;
    srow = b*SROWS + 97 + P;
  }
  const float* ip = inp + (size_t)arr*TLEN;
  float acc = 0.0f;
  int n = 64*t - KC; if (n < 0) n += TLEN;
  if (LAYOUT == 0){
    for (int m=0;m<NTAP;m++){
      acc += ip[n] * w[m];
      n++; if (n == TLEN) n = 0;
    }
  } else {
    int n1 = n % NA, n2 = n / NA;
    for (int m=0;m<NTAP;m++){
      acc += ip[n1*NB + n2] * w[m];
      n1++; if (n1 == NA){ n1 = 0; n2++; if (n2 == NB) n2 = 0; }
    }
  }
  S[(size_t)srow*TD + t] = acc;
}

// ---------------- global min/max + finalize ----------------
__global__ __launch_bounds__(256) void k_minmax1(const float* __restrict__ S, int n, float* pmn, float* pmx){
  __shared__ float smn[256], smx[256];
  float mn = 3.4028235e38f, mx = -3.4028235e38f;
  for (size_t i = (size_t)blockIdx.x*256 + threadIdx.x; i < (size_t)n; i += (size_t)gridDim.x*256){
    float v = S[i]; mn = fminf(mn,v); mx = fmaxf(mx,v);
  }
  smn[threadIdx.x]=mn; smx[threadIdx.x]=mx; __syncthreads();
  for (int s=128;s>0;s>>=1){
    if ((int)threadIdx.x < s){
      smn[threadIdx.x]=fminf(smn[threadIdx.x],smn[threadIdx.x+s]);
      smx[threadIdx.x]=fmaxf(smx[threadIdx.x],smx[threadIdx.x+s]);
    }
    __syncthreads();
  }
  if (threadIdx.x==0){ pmn[blockIdx.x]=smn[0]; pmx[blockIdx.x]=smx[0]; }
}
__global__ __launch_bounds__(256) void k_minmax2(const float* __restrict__ pmn, const float* __restrict__ pmx,
                                                 int nb, float* scal){
  __shared__ float smn[256], smx[256];
  float mn = 3.4028235e38f, mx = -3.4028235e38f;
  for (int i = threadIdx.x; i < nb; i += 256){ mn = fminf(mn,pmn[i]); mx = fmaxf(mx,pmx[i]); }
  smn[threadIdx.x]=mn; smx[threadIdx.x]=mx; __syncthreads();
  for (int s=128;s>0;s>>=1){
    if ((int)threadIdx.x < s){
      smn[threadIdx.x]=fminf(smn[threadIdx.x],smn[threadIdx.x+s]);
      smx[threadIdx.x]=fmaxf(smx[threadIdx.x],smx[threadIdx.x+s]);
    }
    __syncthreads();
  }
  if (threadIdx.x==0){ scal[0]=smn[0]; scal[1]=smx[0]; }
}
__global__ __launch_bounds__(256) void k_final(const float* __restrict__ S, const float* __restrict__ scal,
                                               float* __restrict__ out, int n){
  int i = blockIdx.x*256 + threadIdx.x;
  if (i >= n) return;
  float mn = scal[0];
  float r = scal[1] - mn;
  if (r == 0.0f) r = 1.0f;
  int half = SROWS*TD;
  int a = i / half; int rest = i - a*half;
  out[i] = (S[(size_t)(a & 1)*half + rest] - mn) / r;
}

extern "C" void kernel_launch(void* const* d_in, const int* in_sizes, int n_in,
                              void* d_out, int out_size, void* d_ws, size_t ws_size,
                              hipStream_t stream){
  (void)in_sizes; (void)n_in;
  const float* x = (const float*)d_in[0];

  // pick k1-block size (BLK k1's per block, CH = 2*BLK tasks) to fit workspace
  int BLK = 16;
  while (BLK > 1){
    size_t CH = 2*(size_t)BLK;
    size_t needb = 2560000ULL + 3ULL*CH*TLEN*8ULL + CH*TLEN*4ULL + 6740000ULL + 8192ULL + 4096ULL;
    if (needb <= ws_size) break;
    BLK >>= 1;
  }
  {
    size_t CH = 2;
    size_t needmin = 2560000ULL + 3ULL*CH*TLEN*8ULL + CH*TLEN*4ULL + 6740000ULL + 8192ULL + 4096ULL;
    if (ws_size < needmin) return;  // cannot run safely
  }
  int CH = 2*BLK;

  char* p = (char*)d_ws;
  auto carve = [&](size_t bytes)->void*{ void* r = (void*)p; p += (bytes + 255) & ~(size_t)255; return r; };
  c2*    Xf  = (c2*)carve(2ULL*TLEN*sizeof(c2));
  c2*    A   = (c2*)carve((size_t)CH*TLEN*sizeof(c2));
  c2*    B   = (c2*)carve((size_t)CH*TLEN*sizeof(c2));
  c2*    U1h = (c2*)carve((size_t)CH*TLEN*sizeof(c2));
  float* Ur  = (float*)carve((size_t)CH*TLEN*sizeof(float));
  float* Sb  = (float*)carve(2ULL*SROWS*TD*sizeof(float));
  float* pmn = (float*)carve(512*4);
  float* pmx = (float*)carve(512*4);
  float* scal = (float*)carve(256);

  // ---- forward FFT of x -> Xf (scrambled-freq layout) ----
  k_fft256<-1,2,0><<<2*NA, 64, 0, stream>>>((const void*)x, (void*)A);          // natural x, rows n1, twiddle
  k_transpose<<<2*20*8, 256, 0, stream>>>(A, B, NA, NB, 20, 8);                 // [625][256] -> [256][625]
  k_fft625<-1,0,0><<<2*NB, 128, 0, stream>>>(B, Xf, 0,0,0,0,0);                 // rows kb -> Y[kb][ka]
  // ---- S0 ----
  k_conv<0,0><<<2*10, 256, 0, stream>>>(x, Sb, 0,0,0,0,0);

  int NCB = 96 / BLK;
  for (int c = 0; c < NCB; c++){
    int cq = (c*BLK)/16;
    int nj2 = 5 - cq;
    int j2base = cq + 1;
    // ---- order 1: U1 = |ifft(Xf * psi1)| ----
    k_fft625<1,1,1><<<CH*NB, 128, 0, stream>>>(Xf, A, c, BLK, 0,0,0);           // I1 + psi1 + twiddle -> [kb][n1]
    k_transpose<<<CH*160, 256, 0, stream>>>(A, B, NB, NA, 8, 20);               // -> [n1][kb]
    k_fft256<1,0,1><<<CH*NA, 64, 0, stream>>>((const void*)B, (void*)Ur);       // I3, abs, 1/T -> U1 scrambled
    k_conv<1,1><<<CH*10, 256, 0, stream>>>(Ur, Sb, c, BLK, 0,0,0);              // S1 rows
    if (nj2 > 0){
      // ---- forward FFT of U1 -> U1h ----
      k_fft256<-1,1,0><<<CH*NA, 64, 0, stream>>>((const void*)Ur, (void*)A);    // F1 (real in) + twiddle
      k_transpose<<<CH*160, 256, 0, stream>>>(A, B, NA, NB, 20, 8);             // -> [kb][n1]
      k_fft625<-1,0,0><<<CH*NB, 128, 0, stream>>>(B, U1h, 0,0,0,0,0);           // F3 -> U1h[kb][ka]
      // ---- order 2 paths (uniform nj2 j2's per j1 in this block) ----
      for (int sc = 0; sc < nj2; sc++){
        k_fft625<1,2,1><<<CH*NB, 128, 0, stream>>>(U1h, A, c, BLK, nj2, j2base, sc*CH);
        k_transpose<<<CH*160, 256, 0, stream>>>(A, B, NB, NA, 8, 20);
        k_fft256<1,0,1><<<CH*NA, 64, 0, stream>>>((const void*)B, (void*)Ur);   // U2 scrambled
        k_conv<1,2><<<CH*10, 256, 0, stream>>>(Ur, Sb, c, BLK, nj2, j2base, sc*CH); // S2 rows
      }
    }
  }

  // ---- global min-max normalize (standardize cancels) + tile(3,1,1) ----
  k_minmax1<<<512, 256, 0, stream>>>(Sb, 2*SROWS*TD, pmn, pmx);
  k_minmax2<<<1, 256, 0, stream>>>(pmn, pmx, 512, scal);
  k_final<<<(out_size+255)/256, 256, 0, stream>>>(Sb, scal, (float*)d_out, out_size);
}

// Round 2
// 1785.798 us; speedup vs baseline: 2.3593x; 2.3593x over previous
//
#include <hip/hip_runtime.h>
#include <math.h>

#define TLEN 160000
#define NA 625      // n1 (time rows) / ka (freq elements)
#define NB 256      // n2 (time elements) / kb (freq rows)
#define TD 2500
#define KC 128      // conv half width (~5 sigma_t, sigma_t = 25.46)
#define NTAP 257
#define SROWS 337
#define TWO_PI 6.283185307179586f

struct c2 { float x, y; };

__device__ __forceinline__ c2 cmul(c2 a, c2 b){ return c2{a.x*b.x - a.y*b.y, a.x*b.y + a.y*b.x}; }
__device__ __forceinline__ c2 cadd(c2 a, c2 b){ return c2{a.x+b.x, a.y+b.y}; }
__device__ __forceinline__ c2 csub(c2 a, c2 b){ return c2{a.x-b.x, a.y-b.y}; }
__device__ __forceinline__ c2 cmac(c2 acc, c2 v, float wr, float wi){
  acc.x += v.x*wr - v.y*wi; acc.y += v.x*wi + v.y*wr; return acc;
}
__device__ __forceinline__ c2 cis(float ang){ c2 r; __sincosf(ang, &r.y, &r.x); return r; }
// LDS index swizzle to break power-of-2 bank strides
__device__ __forceinline__ int SW(int i){ return i + (i >> 4); }
// swizzle for stride-64 conv reads: bank = (65t + c) & 31 -> conflict-free
__device__ __forceinline__ int SW64(int i){ return i + (i >> 6); }

__device__ __forceinline__ float omega_of(int k){
  return (k >= TLEN/2 ? (float)(k - TLEN) : (float)k) * (1.0f/(float)TLEN);
}
__device__ __forceinline__ float psi1_val(int j1, int k){
  float xi = 0.4f * exp2f(-(float)j1 * 0.0625f);
  float sig = xi * 0.04427378243f;               // 2^(1/16)-1
  float d = omega_of(k) - xi;
  return __expf(-d*d / (2.0f*sig*sig));
}
__device__ __forceinline__ float psi2_val(int j2, int k){
  float xi = 0.4f * exp2f(-(float)j2);
  float sig = 0.35f * xi;
  float d = omega_of(k) - xi;
  return __expf(-d*d / (2.0f*sig*sig));
}

template<int S>
__device__ __forceinline__ void dft4(c2& a0, c2& a1, c2& a2, c2& a3){
  c2 t0 = cadd(a0,a2), t1 = csub(a0,a2), t2 = cadd(a1,a3), t3 = csub(a1,a3);
  float fs = (float)S;
  a0 = cadd(t0,t2); a2 = csub(t0,t2);
  a1 = c2{t1.x - fs*t3.y, t1.y + fs*t3.x};
  a3 = c2{t1.x + fs*t3.y, t1.y - fs*t3.x};
}

template<int S>
__device__ __forceinline__ void dft5(const c2 a[5], c2 b[5]){
  const float C1 = 0.30901699437494742f, C2 = -0.80901699437494745f;
  const float S1 = 0.95105651629515353f * (float)S, S2 = 0.58778525229247314f * (float)S;
  b[0] = cadd(cadd(a[0],a[1]), cadd(cadd(a[2],a[3]),a[4]));
  c2 r;
  r = a[0]; r = cmac(r,a[1],C1, S1); r = cmac(r,a[2],C2, S2); r = cmac(r,a[3],C2,-S2); r = cmac(r,a[4],C1,-S1); b[1]=r;
  r = a[0]; r = cmac(r,a[1],C2, S2); r = cmac(r,a[2],C1,-S1); r = cmac(r,a[3],C1, S1); r = cmac(r,a[4],C2,-S2); b[2]=r;
  r = a[0]; r = cmac(r,a[1],C2,-S2); r = cmac(r,a[2],C1, S1); r = cmac(r,a[3],C1,-S1); r = cmac(r,a[4],C2, S2); b[3]=r;
  r = a[0]; r = cmac(r,a[1],C1,-S1); r = cmac(r,a[2],C2,-S2); r = cmac(r,a[3],C2, S2); r = cmac(r,a[4],C1, S1); b[4]=r;
}

// ---------------- 256-point row FFT (radix-4 Stockham), one row per 64-thread block ----------------
// INMODE: 0 = complex rows, 1 = real rows (scrambled), 2 = natural-order real gather (x)
// OUTMODE: 0 = complex + row twiddle e^{S*2pi*i*n1*kb/T} (first forward stage)
//          1 = |.| * (1/T) -> float rows (last inverse stage)
template<int S, int INMODE, int OUTMODE>
__global__ __launch_bounds__(64) void k_fft256(const void* __restrict__ inp, void* __restrict__ outp){
  __shared__ c2 lds[2][272];
  int g = blockIdx.x;
  int arr = g / NA, n1 = g - arr*NA;
  int j = threadIdx.x;
  c2 v[4];
  if (INMODE == 0){
    const c2* ip = (const c2*)inp + (size_t)arr*TLEN + (size_t)n1*NB;
    #pragma unroll
    for (int q=0;q<4;q++) v[q] = ip[j + 64*q];
  } else if (INMODE == 1){
    const float* ip = (const float*)inp + (size_t)arr*TLEN + (size_t)n1*NB;
    #pragma unroll
    for (int q=0;q<4;q++) v[q] = c2{ip[j + 64*q], 0.0f};
  } else {
    const float* ip = (const float*)inp + (size_t)arr*TLEN;
    #pragma unroll
    for (int q=0;q<4;q++) v[q] = c2{ip[n1 + NA*(j + 64*q)], 0.0f};
  }
  dft4<S>(v[0],v[1],v[2],v[3]);
  #pragma unroll
  for (int r=0;r<4;r++) lds[0][SW(4*j + r)] = v[r];
  __syncthreads();
  { // L = 4
    int k = j & 3;
    c2 w = cis((float)S * TWO_PI * (float)k * (1.0f/16.0f));
    c2 w2 = cmul(w,w), w3 = cmul(w2,w);
    v[0] = lds[0][SW(j)];
    v[1] = cmul(lds[0][SW(j+64)], w);
    v[2] = cmul(lds[0][SW(j+128)], w2);
    v[3] = cmul(lds[0][SW(j+192)], w3);
    dft4<S>(v[0],v[1],v[2],v[3]);
    int base = 4*(j-k)+k;
    #pragma unroll
    for (int r=0;r<4;r++) lds[1][SW(base + 4*r)] = v[r];
  }
  __syncthreads();
  { // L = 16
    int k = j & 15;
    c2 w = cis((float)S * TWO_PI * (float)k * (1.0f/64.0f));
    c2 w2 = cmul(w,w), w3 = cmul(w2,w);
    v[0] = lds[1][SW(j)];
    v[1] = cmul(lds[1][SW(j+64)], w);
    v[2] = cmul(lds[1][SW(j+128)], w2);
    v[3] = cmul(lds[1][SW(j+192)], w3);
    dft4<S>(v[0],v[1],v[2],v[3]);
    int base = 4*(j-k)+k;
    #pragma unroll
    for (int r=0;r<4;r++) lds[0][SW(base + 16*r)] = v[r];
  }
  __syncthreads();
  { // L = 64 (k = j), outputs kb = j + 64r
    c2 w = cis((float)S * TWO_PI * (float)j * (1.0f/256.0f));
    c2 w2 = cmul(w,w), w3 = cmul(w2,w);
    v[0] = lds[0][SW(j)];
    v[1] = cmul(lds[0][SW(j+64)], w);
    v[2] = cmul(lds[0][SW(j+128)], w2);
    v[3] = cmul(lds[0][SW(j+192)], w3);
    dft4<S>(v[0],v[1],v[2],v[3]);
    if (OUTMODE == 0){
      c2* op = (c2*)outp + (size_t)arr*TLEN + (size_t)n1*NB;
      #pragma unroll
      for (int r=0;r<4;r++){
        int kb = j + 64*r;
        c2 tw = cis((float)S * TWO_PI * (float)(n1*kb) * (1.0f/160000.0f));
        op[kb] = cmul(v[r], tw);
      }
    } else {
      float* op = (float*)outp + (size_t)arr*TLEN + (size_t)n1*NB;
      #pragma unroll
      for (int r=0;r<4;r++){
        c2 z = v[r];
        op[j + 64*r] = sqrtf(z.x*z.x + z.y*z.y) * (1.0f/160000.0f);
      }
    }
  }
}

// ---------------- 625-point row FFT (radix-5 Stockham), one row per 128-thread block ----------------
// FILT: 0 none (input array = task i), 1 psi1 (input = Xf[b]), 2 psi2 (input = U1h[slot])
// TW: multiply output element n1 of row kb by e^{S*2pi*i*n1*kb/T}
template<int S, int FILT, int TW>
__global__ __launch_bounds__(128) void k_fft625(const c2* __restrict__ inp, c2* __restrict__ outp,
                                                int cblk, int BLK, int nj2, int j2base, int scBase){
  __shared__ c2 lds[2][672];
  int g = blockIdx.x;
  int i = g / NB, kb = g - i*NB;
  int j = threadIdx.x;
  c2 a[5], b[5];
  if (j < 125){
    const c2* ip;
    int j1 = 0, j2 = 0;
    if (FILT == 0){
      ip = inp + (size_t)i*TLEN;
    } else if (FILT == 1){
      int bt = i / BLK; j1 = cblk*BLK + (i - bt*BLK);
      ip = inp + (size_t)bt*TLEN;
    } else {
      int g2 = scBase + i;
      int npb = BLK*nj2;
      int bt = g2 / npb, rr = g2 - bt*npb;
      int jloc = rr / nj2; j2 = j2base + (rr - jloc*nj2);
      ip = inp + (size_t)(bt*BLK + jloc)*TLEN;
    }
    ip += (size_t)kb*NA;
    #pragma unroll
    for (int q=0;q<5;q++){
      int ka = j + 125*q;
      c2 val = ip[ka];
      if (FILT == 1){ float f = psi1_val(j1, kb + 256*ka); val.x *= f; val.y *= f; }
      if (FILT == 2){ float f = psi2_val(j2, kb + 256*ka); val.x *= f; val.y *= f; }
      a[q] = val;
    }
    dft5<S>(a, b);
    #pragma unroll
    for (int r=0;r<5;r++) lds[0][SW(5*j + r)] = b[r];
  }
  __syncthreads();
  if (j < 125){ // L = 5
    int k = j % 5;
    c2 w = cis((float)S * TWO_PI * (float)k * (1.0f/25.0f));
    c2 w2 = cmul(w,w), w3 = cmul(w2,w), w4 = cmul(w3,w);
    a[0] = lds[0][SW(j)];
    a[1] = cmul(lds[0][SW(j+125)], w);
    a[2] = cmul(lds[0][SW(j+250)], w2);
    a[3] = cmul(lds[0][SW(j+375)], w3);
    a[4] = cmul(lds[0][SW(j+500)], w4);
    dft5<S>(a, b);
    int base = 5*(j-k)+k;
    #pragma unroll
    for (int r=0;r<5;r++) lds[1][SW(base + 5*r)] = b[r];
  }
  __syncthreads();
  if (j < 125){ // L = 25
    int k = j % 25;
    c2 w = cis((float)S * TWO_PI * (float)k * (1.0f/125.0f));
    c2 w2 = cmul(w,w), w3 = cmul(w2,w), w4 = cmul(w3,w);
    a[0] = lds[1][SW(j)];
    a[1] = cmul(lds[1][SW(j+125)], w);
    a[2] = cmul(lds[1][SW(j+250)], w2);
    a[3] = cmul(lds[1][SW(j+375)], w3);
    a[4] = cmul(lds[1][SW(j+500)], w4);
    dft5<S>(a, b);
    int base = 5*(j-k)+k;
    #pragma unroll
    for (int r=0;r<5;r++) lds[0][SW(base + 25*r)] = b[r];
  }
  __syncthreads();
  if (j < 125){ // L = 125 (k = j), outputs n1 = j + 125r
    c2 w = cis((float)S * TWO_PI * (float)j * (1.0f/625.0f));
    c2 w2 = cmul(w,w), w3 = cmul(w2,w), w4 = cmul(w3,w);
    a[0] = lds[0][SW(j)];
    a[1] = cmul(lds[0][SW(j+125)], w);
    a[2] = cmul(lds[0][SW(j+250)], w2);
    a[3] = cmul(lds[0][SW(j+375)], w3);
    a[4] = cmul(lds[0][SW(j+500)], w4);
    dft5<S>(a, b);
    c2* op = outp + (size_t)i*TLEN + (size_t)kb*NA;
    #pragma unroll
    for (int r=0;r<5;r++){
      int n1 = j + 125*r;
      c2 z = b[r];
      if (TW){
        c2 tw = cis((float)S * TWO_PI * (float)(n1*kb) * (1.0f/160000.0f));
        z = cmul(z, tw);
      }
      op[n1] = z;
    }
  }
}

// ---------------- complex transpose [R][C] -> [C][R], per array ----------------
__global__ __launch_bounds__(256) void k_transpose(const c2* __restrict__ in, c2* __restrict__ out,
                                                   int R, int C, int tilesR, int tilesC){
  __shared__ c2 tile[32][33];
  int bi = blockIdx.x;
  int arr = bi / (tilesR*tilesC);
  int tt = bi - arr*(tilesR*tilesC);
  int tr = tt / tilesC, tc = tt - tr*tilesC;
  const c2* ip = in + (size_t)arr*TLEN;
  c2* op = out + (size_t)arr*TLEN;
  int tx = threadIdx.x & 31, ty = threadIdx.x >> 5;
  #pragma unroll
  for (int i=0;i<4;i++){
    int r = tr*32 + ty + i*8, cc = tc*32 + tx;
    if (r < R && cc < C) tile[ty+i*8][tx] = ip[(size_t)r*C + cc];
  }
  __syncthreads();
  #pragma unroll
  for (int i=0;i<4;i++){
    int r = tc*32 + ty + i*8, cc = tr*32 + tx;
    if (r < C && cc < R) op[(size_t)r*R + cc] = tile[tx][ty+i*8];
  }
}

// ---------------- Gaussian lowpass + decimate-by-64, natural layout (S0 only) ----------------
__global__ __launch_bounds__(256) void k_conv(const float* __restrict__ inp, float* __restrict__ S){
  __shared__ float w[NTAP];
  for (int i=threadIdx.x; i<NTAP; i+=256){
    float d = (float)(i - KC);
    w[i] = 0.015666427f * __expf(-7.7106284e-4f * d * d);
  }
  __syncthreads();
  int g = blockIdx.x;
  int arr = g / 10;
  int t = (g - arr*10)*256 + threadIdx.x;
  if (t >= TD) return;
  int srow = arr * SROWS;
  const float* ip = inp + (size_t)arr*TLEN;
  float acc = 0.0f;
  int n = 64*t - KC; if (n < 0) n += TLEN;
  for (int m=0;m<NTAP;m++){
    acc += ip[n] * w[m];
    n++; if (n == TLEN) n = 0;
  }
  S[(size_t)srow*TD + t] = acc;
}

// ---------------- fused LDS stage + conv for scrambled-layout U (S1/S2 rows) ----------------
// Block = (arr, b): outputs t in [250b, 250b+250). Stages 27 full 625-columns of the
// scrambled [n1][n2] array into LDS in natural time order (SW64-swizzled), then each
// thread does the 257-tap dot product from LDS (bank-conflict-free: (65t+c)&31).
// MODE: 1 -> S1 rows, 2 -> S2 rows
#define CONV_NCOL 27
#define CONV_NU   16875   // 27*625
#define CONV_USZ  17138   // SW64(16874)+1
#define CONV_LDSB ((CONV_USZ + NTAP + 1)*4)
template<int MODE>
__global__ __launch_bounds__(256) void k_conv2(const float* __restrict__ inp, float* __restrict__ S,
                                               int cblk, int BLK, int nj2, int j2base, int scBase){
  extern __shared__ float smem[];
  float* u = smem;
  float* w = smem + CONV_USZ;
  for (int i=threadIdx.x; i<NTAP; i+=256){
    float d = (float)(i - KC);
    w[i] = 0.015666427f * __expf(-7.7106284e-4f * d * d);
  }
  int g = blockIdx.x;
  int arr = g / 10;
  int b = g - arr*10;
  int nlo = 16000*b - KC;                       // first time sample needed
  int n2_0 = (nlo >= 0) ? (nlo/625) : -1;       // floor division (nlo >= -128)
  const float* ip = inp + (size_t)arr*TLEN;
  // stage: column c (n2 = (n2_0+c) mod 256), rows n1 = 0..624 -> u[n1 + 625*c]
  for (int e = threadIdx.x; e < CONV_NU; e += 256){
    int n1 = e / CONV_NCOL;
    int c  = e - n1*CONV_NCOL;
    int n2 = n2_0 + c;
    n2 &= 255;                                   // mod 256 (handles wrap, n2_0>=-1)
    u[SW64(n1 + 625*c)] = ip[n1*NB + n2];
  }
  __syncthreads();
  int tl = threadIdx.x;
  if (tl >= 250) return;
  int t = 250*b + tl;
  int srow;
  if (MODE == 1){
    int a2 = arr / BLK; int j1 = cblk*BLK + (arr - a2*BLK);
    srow = a2*SROWS + 1 + j1;
  } else {
    int g2 = scBase + arr; int npb = BLK*nj2;
    int a2 = g2/npb, rr = g2 - a2*npb;
    int jloc = rr/nj2; int j2 = j2base + (rr - jloc*nj2);
    int j1 = cblk*BLK + jloc;
    int full = j1 >> 4;
    int cum = 16*(5*full - (full*(full-1))/2) + (j1 & 15)*(5 - full);
    int P = cum + j2 - full - 1;
    srow = a2*SROWS + 97 + P;
  }
  int base = 64*t - KC - 625*n2_0;               // local natural-time offset, >= 0
  float acc = 0.0f;
  #pragma unroll 4
  for (int m=0;m<NTAP;m++){
    acc += u[SW64(base + m)] * w[m];
  }
  S[(size_t)srow*TD + t] = acc;
}

// ---------------- global min/max + finalize ----------------
__global__ __launch_bounds__(256) void k_minmax1(const float* __restrict__ S, int n, float* pmn, float* pmx){
  __shared__ float smn[256], smx[256];
  float mn = 3.4028235e38f, mx = -3.4028235e38f;
  for (size_t i = (size_t)blockIdx.x*256 + threadIdx.x; i < (size_t)n; i += (size_t)gridDim.x*256){
    float v = S[i]; mn = fminf(mn,v); mx = fmaxf(mx,v);
  }
  smn[threadIdx.x]=mn; smx[threadIdx.x]=mx; __syncthreads();
  for (int s=128;s>0;s>>=1){
    if ((int)threadIdx.x < s){
      smn[threadIdx.x]=fminf(smn[threadIdx.x],smn[threadIdx.x+s]);
      smx[threadIdx.x]=fmaxf(smx[threadIdx.x],smx[threadIdx.x+s]);
    }
    __syncthreads();
  }
  if (threadIdx.x==0){ pmn[blockIdx.x]=smn[0]; pmx[blockIdx.x]=smx[0]; }
}
__global__ __launch_bounds__(256) void k_minmax2(const float* __restrict__ pmn, const float* __restrict__ pmx,
                                                 int nb, float* scal){
  __shared__ float smn[256], smx[256];
  float mn = 3.4028235e38f, mx = -3.4028235e38f;
  for (int i = threadIdx.x; i < nb; i += 256){ mn = fminf(mn,pmn[i]); mx = fmaxf(mx,pmx[i]); }
  smn[threadIdx.x]=mn; smx[threadIdx.x]=mx; __syncthreads();
  for (int s=128;s>0;s>>=1){
    if ((int)threadIdx.x < s){
      smn[threadIdx.x]=fminf(smn[threadIdx.x],smn[threadIdx.x+s]);
      smx[threadIdx.x]=fmaxf(smx[threadIdx.x],smx[threadIdx.x+s]);
    }
    __syncthreads();
  }
  if (threadIdx.x==0){ scal[0]=smn[0]; scal[1]=smx[0]; }
}
__global__ __launch_bounds__(256) void k_final(const float* __restrict__ S, const float* __restrict__ scal,
                                               float* __restrict__ out, int n){
  int i = blockIdx.x*256 + threadIdx.x;
  if (i >= n) return;
  float mn = scal[0];
  float r = scal[1] - mn;
  if (r == 0.0f) r = 1.0f;
  int half = SROWS*TD;
  int a = i / half; int rest = i - a*half;
  out[i] = (S[(size_t)(a & 1)*half + rest] - mn) / r;
}

extern "C" void kernel_launch(void* const* d_in, const int* in_sizes, int n_in,
                              void* d_out, int out_size, void* d_ws, size_t ws_size,
                              hipStream_t stream){
  (void)in_sizes; (void)n_in;
  const float* x = (const float*)d_in[0];

  // pick k1-block size (BLK k1's per block, CH = 2*BLK tasks) to fit workspace
  int BLK = 16;
  while (BLK > 1){
    size_t CH = 2*(size_t)BLK;
    size_t needb = 2560000ULL + 3ULL*CH*TLEN*8ULL + CH*TLEN*4ULL + 6740000ULL + 8192ULL + 4096ULL;
    if (needb <= ws_size) break;
    BLK >>= 1;
  }
  {
    size_t CH = 2;
    size_t needmin = 2560000ULL + 3ULL*CH*TLEN*8ULL + CH*TLEN*4ULL + 6740000ULL + 8192ULL + 4096ULL;
    if (ws_size < needmin) return;  // cannot run safely
  }
  int CH = 2*BLK;

  char* p = (char*)d_ws;
  auto carve = [&](size_t bytes)->void*{ void* r = (void*)p; p += (bytes + 255) & ~(size_t)255; return r; };
  c2*    Xf  = (c2*)carve(2ULL*TLEN*sizeof(c2));
  c2*    A   = (c2*)carve((size_t)CH*TLEN*sizeof(c2));
  c2*    B   = (c2*)carve((size_t)CH*TLEN*sizeof(c2));
  c2*    U1h = (c2*)carve((size_t)CH*TLEN*sizeof(c2));
  float* Ur  = (float*)carve((size_t)CH*TLEN*sizeof(float));
  float* Sb  = (float*)carve(2ULL*SROWS*TD*sizeof(float));
  float* pmn = (float*)carve(512*4);
  float* pmx = (float*)carve(512*4);
  float* scal = (float*)carve(256);

  // ---- forward FFT of x -> Xf (scrambled-freq layout) ----
  k_fft256<-1,2,0><<<2*NA, 64, 0, stream>>>((const void*)x, (void*)A);          // natural x, rows n1, twiddle
  k_transpose<<<2*20*8, 256, 0, stream>>>(A, B, NA, NB, 20, 8);                 // [625][256] -> [256][625]
  k_fft625<-1,0,0><<<2*NB, 128, 0, stream>>>(B, Xf, 0,0,0,0,0);                 // rows kb -> Y[kb][ka]
  // ---- S0 ----
  k_conv<<<2*10, 256, 0, stream>>>(x, Sb);

  int NCB = 96 / BLK;
  for (int c = 0; c < NCB; c++){
    int cq = (c*BLK)/16;
    int nj2 = 5 - cq;
    int j2base = cq + 1;
    // ---- order 1: U1 = |ifft(Xf * psi1)| ----
    k_fft625<1,1,1><<<CH*NB, 128, 0, stream>>>(Xf, A, c, BLK, 0,0,0);           // I1 + psi1 + twiddle -> [kb][n1]
    k_transpose<<<CH*160, 256, 0, stream>>>(A, B, NB, NA, 8, 20);               // -> [n1][kb]
    k_fft256<1,0,1><<<CH*NA, 64, 0, stream>>>((const void*)B, (void*)Ur);       // I3, abs, 1/T -> U1 scrambled
    k_conv2<1><<<CH*10, 256, CONV_LDSB, stream>>>(Ur, Sb, c, BLK, 0,0,0);       // S1 rows
    if (nj2 > 0){
      // ---- forward FFT of U1 -> U1h ----
      k_fft256<-1,1,0><<<CH*NA, 64, 0, stream>>>((const void*)Ur, (void*)A);    // F1 (real in) + twiddle
      k_transpose<<<CH*160, 256, 0, stream>>>(A, B, NA, NB, 20, 8);             // -> [kb][n1]
      k_fft625<-1,0,0><<<CH*NB, 128, 0, stream>>>(B, U1h, 0,0,0,0,0);           // F3 -> U1h[kb][ka]
      // ---- order 2 paths (uniform nj2 j2's per j1 in this block) ----
      for (int sc = 0; sc < nj2; sc++){
        k_fft625<1,2,1><<<CH*NB, 128, 0, stream>>>(U1h, A, c, BLK, nj2, j2base, sc*CH);
        k_transpose<<<CH*160, 256, 0, stream>>>(A, B, NB, NA, 8, 20);
        k_fft256<1,0,1><<<CH*NA, 64, 0, stream>>>((const void*)B, (void*)Ur);   // U2 scrambled
        k_conv2<2><<<CH*10, 256, CONV_LDSB, stream>>>(Ur, Sb, c, BLK, nj2, j2base, sc*CH); // S2 rows
      }
    }
  }

  // ---- global min-max normalize (standardize cancels) + tile(3,1,1) ----
  k_minmax1<<<512, 256, 0, stream>>>(Sb, 2*SROWS*TD, pmn, pmx);
  k_minmax2<<<1, 256, 0, stream>>>(pmn, pmx, 512, scal);
  k_final<<<(out_size+255)/256, 256, 0, stream>>>(Sb, scal, (float*)d_out, out_size);
}